// Round 7
// baseline (44.544 us; speedup 1.0000x reference)
//
#include <hip/hip_runtime.h>

#define GRIDN 256
#define NROW  128       // rows per side
#define ZB    104       // bucket window base: u in [0,1) => z in [110,160] ⊂ [104,168)
#define ZW    64        // window width (quads preserved by swizzle)

__global__ __launch_bounds__(1024, 8)
void consist_loss_kernel(const float* __restrict__ up,
                         const float* __restrict__ left,
                         const float* __restrict__ right,
                         unsigned int* __restrict__ counter,   // d_ws[0], zeroed per launch
                         float* __restrict__ partials,         // d_ws + 64 floats
                         float* __restrict__ out,
                         int nblocks)
{
    __shared__ unsigned int bk[GRIDN * ZW];   // [col][z'] u32, quad-swizzled; 64 KB
    __shared__ float tab[128];
    __shared__ float wsum[16];
    __shared__ double sm[256];
    __shared__ int islast;

    const int t    = threadIdx.x;             // 0..1023
    const int bid  = blockIdx.x;
    const int side = bid & 1;                 // 0 = left, 1 = right
    const int b    = bid >> 1;                // batch
    const int lane = t & 63;
    const int w    = t >> 6;                  // wave 0..15

    // ---- EARLY ISSUE: phase-2 window image loads (consumed after the barrier).
    const float* img = (side ? right : left) + (size_t)b * (GRIDN * GRIDN);
    const int g  = lane & 3;
    const int z0 = (lane >> 2) * 4;            // quad base, 0..60
    float4 ximg[4];
    #pragma unroll
    for (int i = 0; i < 4; ++i) {
        const int col = w * 16 + 4 * g + i;
        ximg[i] = *(const float4*)(img + (size_t)col * GRIDN + ZB + z0);
    }

    // ---- EARLY ISSUE: up rows
    const int col4 = lane * 4;
    const float* upb = up + (size_t)b * (GRIDN * GRIDN)
                          + (size_t)(side * NROW + w * 8) * GRIDN + col4;
    float4 u0 = *(const float4*)(upb + 0 * GRIDN);
    float4 u1 = *(const float4*)(upb + 1 * GRIDN);
    float4 u2 = *(const float4*)(upb + 2 * GRIDN);
    float4 u3 = *(const float4*)(upb + 3 * GRIDN);

    // ---- bucket init (uint4 stores) + value table
    const unsigned int sent = side ? 0u : 0xFFFFFFFFu;  // right: atomicMax; left: atomicMin
    const uint4 s4 = make_uint4(sent, sent, sent, sent);
    #pragma unroll
    for (int i = 0; i < 4; ++i)
        *(uint4*)&bk[4 * t + 4096 * i] = s4;
    if (t < 128) {
        float m = (float)t;
        tab[t] = side ? (m / 60.0f) : ((128.0f - m) / 60.0f); // IEEE div, matches np
    }
    __syncthreads();

    // ---- phase 1: min/max scatter of row index into z buckets.
    const unsigned int k1 = (unsigned)((lane & 15) << 2);  // == ((col>>2)&15)<<2
    unsigned int* bks = bk + col4 * ZW;
    const unsigned int rb = (unsigned)(w * 8);

    auto scatter = [&](float4 u, unsigned int r) {
        float us[4] = {u.x, u.y, u.z, u.w};
        #pragma unroll
        for (int j = 0; j < 4; ++j) {
            float zf = rintf(__fadd_rn(__fmul_rn(us[j], 50.0f), 110.0f)); // no FMA, half-even
            int z  = (int)fminf(fmaxf(zf, 0.0f), 255.0f);
            int zi = min(max(z - ZB, 0), ZW - 1);          // never clamps for u in [0,1)
            if (side) atomicMax(&bks[j * ZW + (zi ^ k1)], r + 1u); // max r; sentinel 0
            else      atomicMin(&bks[j * ZW + (zi ^ k1)], r);      // min r; sentinel ~0
        }
    };

    float4 u4 = *(const float4*)(upb + 4 * GRIDN);
    float4 u5 = *(const float4*)(upb + 5 * GRIDN);
    float4 u6 = *(const float4*)(upb + 6 * GRIDN);
    float4 u7 = *(const float4*)(upb + 7 * GRIDN);
    scatter(u0, rb + 0); scatter(u1, rb + 1); scatter(u2, rb + 2); scatter(u3, rb + 3);
    scatter(u4, rb + 4); scatter(u5, rb + 5); scatter(u6, rb + 6); scatter(u7, rb + 7);
    __syncthreads();

    // ---- phase 2: pure LDS+VALU (image already in ximg registers).
    float acc = 0.0f;
    #pragma unroll
    for (int i = 0; i < 4; ++i) {
        const int col = w * 16 + 4 * g + i;
        const unsigned int k2 = (unsigned)(((col >> 2) & 15) << 2);
        const uint4 vq = *(const uint4*)&bk[col * ZW + (z0 ^ (int)k2)];
        unsigned int vs[4] = {vq.x, vq.y, vq.z, vq.w};
        float xs[4] = {ximg[i].x, ximg[i].y, ximg[i].z, ximg[i].w};
        #pragma unroll
        for (int j = 0; j < 4; ++j) {
            unsigned int v = vs[j];
            bool valid; int m;
            if (side) { valid = (v >= 2u); m = (int)v - 1; }   // r=0 -> value 0 excluded
            else      { valid = (v != 0xFFFFFFFFu); m = (int)v; }
            if (valid) {
                float d = fabsf(tab[m] - xs[j]);
                if (d < 0.2f) acc += d;
            }
        }
    }

    // ---- block reduction: wave shuffle -> LDS -> single value
    #pragma unroll
    for (int off = 32; off > 0; off >>= 1)
        acc += __shfl_down(acc, off);
    if (lane == 0) wsum[w] = acc;
    __syncthreads();

    // ---- publish partial + last-block-done detection (fused finalize)
    if (t == 0) {
        float s = 0.0f;
        #pragma unroll
        for (int i = 0; i < 16; ++i) s += wsum[i];
        atomicExch(&partials[bid], s);          // device-scope write-through
        __threadfence();                        // release: partial visible before count
        unsigned int old = atomicAdd(counter, 1u);
        islast = (old == (unsigned)(nblocks - 1)) ? 1 : 0;
    }
    __syncthreads();
    if (!islast) return;

    // ---- last block: reduce all partials in fixed order, write output
    __threadfence();                            // acquire
    if (t < 256) {
        double s = 0.0;
        for (int i = t; i < nblocks; i += 256)
            s += (double)atomicAdd(&partials[i], 0.0f);  // coherent read
        sm[t] = s;
    }
    __syncthreads();
    for (int hw = 128; hw > 0; hw >>= 1) {
        if (t < hw) sm[t] += sm[t + hw];
        __syncthreads();
    }
    if (t == 0)
        out[0] = (float)(sm[0] * (1.0 / (65536.0 * 256.0)));
}

extern "C" void kernel_launch(void* const* d_in, const int* in_sizes, int n_in,
                              void* d_out, int out_size, void* d_ws, size_t ws_size,
                              hipStream_t stream) {
    const float* up    = (const float*)d_in[0];
    const float* left  = (const float*)d_in[1];
    const float* right = (const float*)d_in[2];
    unsigned int* counter = (unsigned int*)d_ws;
    float* partials = (float*)d_ws + 64;

    const int B = in_sizes[0] / (GRIDN * GRIDN);   // 256
    const int blocks = B * 2;                      // (batch) x (side)

    hipMemsetAsync(d_ws, 0, 64 * sizeof(float), stream);  // zero the counter
    consist_loss_kernel<<<blocks, 1024, 0, stream>>>(up, left, right,
                                                     counter, partials,
                                                     (float*)d_out, blocks);
}

// Round 8
// 27.149 us; speedup vs baseline: 1.6407x; 1.6407x over previous
//
#include <hip/hip_runtime.h>

#define GRIDN 256
#define NROW  128       // rows per side
#define ZB    104       // bucket window base: u in [0,1) => z in [110,160] subset [104,168)
#define ZW    64        // window width (quad-aligned)

__global__ __launch_bounds__(1024, 8)
void consist_loss_kernel(const float* __restrict__ up,
                         const float* __restrict__ left,
                         const float* __restrict__ right,
                         float* __restrict__ partials)
{
    __shared__ unsigned int bk[GRIDN * ZW];   // [col][z'] u32, swizzled; 64 KB
    __shared__ float tab[128];
    __shared__ float wsum[16];

    const int t    = threadIdx.x;             // 0..1023
    const int bid  = blockIdx.x;
    const int side = bid & 1;                 // 0 = left, 1 = right
    const int b    = bid >> 1;                // batch

    // init buckets: left -> 0xFFFFFFFF (atomicMin), right -> 0 (atomicMax)
    const unsigned int sent = side ? 0u : 0xFFFFFFFFu;
    #pragma unroll
    for (int i = 0; i < (GRIDN * ZW) / 1024; ++i)   // 16 dword stores
        bk[t + 1024 * i] = sent;

    // value table (IEEE f32 div, matches np): left v=(128-m)/60, right v=m/60
    if (t < 128) {
        float m = (float)t;
        tab[t] = side ? (m / 60.0f) : ((128.0f - m) / 60.0f);
    }
    __syncthreads();

    // ---- phase 1: min/max scatter of row index into z buckets.
    // wave w (0..15) handles rows w*8..w*8+7; lane handles 4 columns (float4 load,
    // 1 KB contiguous per wave-load instruction).
    const int lane = t & 63;
    const int w    = t >> 6;
    const int col4 = lane * 4;
    const int k1   = lane & 31;               // == (col4>>2)&31, shared by the 4 cols
    const float* upb = up + (size_t)b * (GRIDN * GRIDN)
                          + (size_t)(side * NROW + w * 8) * GRIDN + col4;
    unsigned int* bks = bk + col4 * ZW;

    #pragma unroll 4
    for (int i = 0; i < 8; ++i) {
        float4 u = *(const float4*)(upb + (size_t)i * GRIDN);
        const unsigned int r = (unsigned int)(w * 8 + i);
        float us[4] = {u.x, u.y, u.z, u.w};
        #pragma unroll
        for (int j = 0; j < 4; ++j) {
            float zf = rintf(__fadd_rn(__fmul_rn(us[j], 50.0f), 110.0f)); // no FMA, half-even
            int z  = (int)fminf(fmaxf(zf, 0.0f), 255.0f);
            int zi = min(max(z - ZB, 0), ZW - 1);   // never clamps for u in [0,1)
            if (side) atomicMax(&bks[j * ZW + (zi ^ k1)], r + 1u); // max r; sentinel 0
            else      atomicMin(&bks[j * ZW + (zi ^ k1)], r);      // min r; sentinel ~0
        }
    }
    __syncthreads();

    // ---- phase 2: compare buckets vs image inside the window only.
    // lane -> (qd = lane>>2, g = lane&3); col = 16w + 4g + i so the 4 col-groups
    // in a wave differ in col>>2 -> swizzled bucket reads are 2-way (free).
    const float* img = (side ? right : left) + (size_t)b * (GRIDN * GRIDN);
    const int g  = t & 3;
    const int z0 = ((t >> 2) & 15) * 4;
    float acc = 0.0f;
    #pragma unroll
    for (int i = 0; i < 4; ++i) {
        const int col = w * 16 + 4 * g + i;
        const int k2  = (col >> 2) & 31;
        const unsigned int* s = bk + col * ZW;
        unsigned int vs[4];
        vs[0] = s[(z0 + 0) ^ k2];
        vs[1] = s[(z0 + 1) ^ k2];
        vs[2] = s[(z0 + 2) ^ k2];
        vs[3] = s[(z0 + 3) ^ k2];
        float4 x = *(const float4*)(img + (size_t)col * GRIDN + ZB + z0);
        float xs[4] = {x.x, x.y, x.z, x.w};
        #pragma unroll
        for (int j = 0; j < 4; ++j) {
            unsigned int v = vs[j];
            bool valid; int m;
            if (side) { valid = (v >= 2u); m = (int)v - 1; }   // r=0 -> value 0 excluded
            else      { valid = (v != 0xFFFFFFFFu); m = (int)v; }
            if (valid) {
                float d = fabsf(tab[m] - xs[j]);
                if (d < 0.2f) acc += d;
            }
        }
    }

    // ---- reduction: wave shuffle -> LDS -> single store per block
    #pragma unroll
    for (int off = 32; off > 0; off >>= 1)
        acc += __shfl_down(acc, off);
    if (lane == 0) wsum[w] = acc;
    __syncthreads();
    if (t == 0) {
        float s = 0.0f;
        #pragma unroll
        for (int i = 0; i < 16; ++i) s += wsum[i];
        partials[bid] = s;
    }
}

__global__ void finalize_kernel(const float* __restrict__ partials, int n,
                                float* __restrict__ out)
{
    __shared__ double sm[256];
    double s = 0.0;
    for (int i = threadIdx.x; i < n; i += 256) s += (double)partials[i];
    sm[threadIdx.x] = s;
    __syncthreads();
    for (int w = 128; w > 0; w >>= 1) {
        if ((int)threadIdx.x < w) sm[threadIdx.x] += sm[threadIdx.x + w];
        __syncthreads();
    }
    if (threadIdx.x == 0)
        out[0] = (float)(sm[0] * (1.0 / (65536.0 * 256.0)));
}

extern "C" void kernel_launch(void* const* d_in, const int* in_sizes, int n_in,
                              void* d_out, int out_size, void* d_ws, size_t ws_size,
                              hipStream_t stream) {
    const float* up    = (const float*)d_in[0];
    const float* left  = (const float*)d_in[1];
    const float* right = (const float*)d_in[2];
    float* partials = (float*)d_ws;

    const int B = in_sizes[0] / (GRIDN * GRIDN);   // 256
    const int blocks = B * 2;                      // (batch) x (side)

    consist_loss_kernel<<<blocks, 1024, 0, stream>>>(up, left, right, partials);
    finalize_kernel<<<1, 256, 0, stream>>>(partials, blocks, (float*)d_out);
}